// Round 5
// baseline (89.151 us; speedup 1.0000x reference)
//
#include <hip/hip_runtime.h>
#include <hip/hip_bf16.h>

#define F      128
#define NROWS  2048
#define MROWS  2048
#define BN     64          // n-rows per pair block
#define BM     64          // m-cols per pair block
#define MT     (MROWS/BM)  // 32 m-tiles
#define GC     16          // g-chunk
#define NCH    (F/GC)      // 8 chunks
#define LW     20          // LDS row stride (floats): 16B-aligned, 20*8=160≡0(32) -> consecutive rows hit distinct banks
#define LOG2E  1.44269504088896340736f

typedef float f32x4 __attribute__((ext_vector_type(4)));

// --- Kernel 1: projections + ELU/w2 precompute + w2sum ----------------------
// a = (embeds@W1)[n][g], b = (base@W1)[m][g], w = w2[g]
// A1W = (a+1)*w   AEW = exp(a)*w   B1W = b*w   BE = exp(-b)
// then w*elu(a-b) + w = med3(A1W - B1W, AEW*BE, w)   [median commutes with *w]
__global__ __launch_bounds__(256) void proj_kernel(
    const float* __restrict__ embeds, const float* __restrict__ base,
    const float* __restrict__ W1, const float* __restrict__ w2,
    float* __restrict__ A1W, float* __restrict__ AEW,
    float* __restrict__ B1W, float* __restrict__ BEp,
    float* __restrict__ w2sum)
{
    const int tid = threadIdx.x;
    const int sub = tid >> 7;
    const int g   = tid & 127;
    const int row = blockIdx.x * 2 + sub;

    __shared__ float xs[2][F];
    {
        const float* src = (row < NROWS) ? &embeds[(size_t)row * F]
                                         : &base[(size_t)(row - NROWS) * F];
        xs[sub][g] = src[g];
    }
    __syncthreads();

    float acc = 0.0f;
#pragma unroll 8
    for (int f = 0; f < F; ++f)
        acc = fmaf(xs[sub][f], W1[f * F + g], acc);

    const float w = w2[g];
    if (row < NROWS) {
        const size_t idx = (size_t)row * F + g;
        A1W[idx] = (acc + 1.0f) * w;
        AEW[idx] = __builtin_amdgcn_exp2f(acc * LOG2E) * w;
    } else {
        const size_t idx = (size_t)(row - NROWS) * F + g;
        B1W[idx] = acc * w;
        BEp[idx] = __builtin_amdgcn_exp2f(-acc * LOG2E);
    }

    if (blockIdx.x == 0 && tid < 64) {
        float s = w2[tid] + w2[tid + 64];
#pragma unroll
        for (int k = 1; k < 64; k <<= 1) s += __shfl_xor(s, k);
        if (tid == 0) *w2sum = s;
    }
}

// --- Kernel 2: pair kernel -----------------------------------------------------
// ONE wave (64 threads) per block, tile 64x64, Rn=Rm=8, NO barriers.
// lane: tr=lane>>3 (0..7), tc=lane&7 (0..7).
// Thread owns rows n = n0 + tr + 8i, cols m = m0 + tc + 8j  (i,j < 8).
// Per element: acc += med3(a1w - b1w, aew*be, w_g)   -- 4 VALU ops.
__global__ __launch_bounds__(64) void pair_kernel(
    const float* __restrict__ A1W, const float* __restrict__ AEW,
    const float* __restrict__ B1W, const float* __restrict__ BEp,
    const float* __restrict__ w2, const float* __restrict__ w2sum_p,
    const float* __restrict__ brew, float* __restrict__ partials)
{
    __shared__ float sA1[BN][LW], sAE[BN][LW];
    __shared__ float sB1[BM][LW], sBE[BM][LW];

    const int lane = threadIdx.x;
    const int nt   = blockIdx.x;
    const int mt   = blockIdx.y;
    const int n0   = nt * BN;
    const int m0   = mt * BM;
    const int tr   = lane >> 3;
    const int tc   = lane & 7;

    const float* pA1 = A1W + (size_t)n0 * F;
    const float* pAE = AEW + (size_t)n0 * F;
    const float* pB1 = B1W + (size_t)m0 * F;
    const float* pBE = BEp + (size_t)m0 * F;

    float acc[8][8];
#pragma unroll
    for (int i = 0; i < 8; ++i)
#pragma unroll
        for (int j = 0; j < 8; ++j) acc[i][j] = 0.0f;

#define STAGE_PLANE(SRC, DST)                                              \
    _Pragma("unroll")                                                      \
    for (int rnd = 0; rnd < 4; ++rnd) {                                    \
        const int idx = rnd * 64 + lane;                                   \
        const int r = idx >> 2, c = (idx & 3) * 4;                         \
        *(f32x4*)&DST[r][c] = *(const f32x4*)&SRC[(size_t)r * F + g0 + c]; \
    }

#pragma unroll 1
    for (int ch = 0; ch < NCH; ++ch) {
        const int g0 = ch * GC;
        STAGE_PLANE(pA1, sA1)
        STAGE_PLANE(pAE, sAE)
        STAGE_PLANE(pB1, sB1)
        STAGE_PLANE(pBE, sBE)
        // single wave: in-order DS pipe + compiler lgkmcnt handles RAW/WAR; no barrier.

#pragma unroll 1
        for (int g4 = 0; g4 < GC; g4 += 4) {
            const f32x4 wv = *(const f32x4*)&w2[g0 + g4];   // wave-uniform
            f32x4 b1v[8], bev[8];
#pragma unroll
            for (int j = 0; j < 8; ++j) {
                b1v[j] = *(const f32x4*)&sB1[tc + 8 * j][g4];
                bev[j] = *(const f32x4*)&sBE[tc + 8 * j][g4];
            }
#pragma unroll
            for (int i = 0; i < 8; ++i) {
                const f32x4 a1 = *(const f32x4*)&sA1[tr + 8 * i][g4];
                const f32x4 ae = *(const f32x4*)&sAE[tr + 8 * i][g4];
#pragma unroll
                for (int j = 0; j < 8; ++j) {
                    float d = acc[i][j];
                    d += __builtin_amdgcn_fmed3f(a1.x - b1v[j].x, ae.x * bev[j].x, wv.x);
                    d += __builtin_amdgcn_fmed3f(a1.y - b1v[j].y, ae.y * bev[j].y, wv.y);
                    d += __builtin_amdgcn_fmed3f(a1.z - b1v[j].z, ae.z * bev[j].z, wv.z);
                    d += __builtin_amdgcn_fmed3f(a1.w - b1v[j].w, ae.w * bev[j].w, wv.w);
                    acc[i][j] = d;
                }
            }
        }
    }
#undef STAGE_PLANE

    const float w2sum = *w2sum_p;
    float rsv[8];
#pragma unroll
    for (int j = 0; j < 8; ++j) rsv[j] = brew[m0 + tc + 8 * j];

#pragma unroll
    for (int i = 0; i < 8; ++i) {
        float sw = 0.0f, swr = 0.0f;
#pragma unroll
        for (int j = 0; j < 8; ++j) {
            const float dist = fabsf(acc[i][j] - w2sum);
            const float w = 1.0f / (dist + 1e-4f);
            sw += w;
            swr = fmaf(w, rsv[j], swr);
        }
#pragma unroll
        for (int k = 1; k < 8; k <<= 1) {   // reduce across tc (low 3 lane bits)
            sw  += __shfl_xor(sw, k);
            swr += __shfl_xor(swr, k);
        }
        if (tc == 0) {
            const int n = n0 + tr + 8 * i;
            partials[((size_t)n * MT + mt) * 2 + 0] = sw;
            partials[((size_t)n * MT + mt) * 2 + 1] = swr;
        }
    }
}

// --- Kernel 3: reduce tile partials, divide ------------------------------------
__global__ __launch_bounds__(256) void finalize_kernel(
    const float* __restrict__ partials, float* __restrict__ out)
{
    const int n = blockIdx.x * 256 + threadIdx.x;
    if (n < NROWS) {
        float sw = 0.0f, swr = 0.0f;
#pragma unroll
        for (int t = 0; t < MT; ++t) {
            sw  += partials[((size_t)n * MT + t) * 2 + 0];
            swr += partials[((size_t)n * MT + t) * 2 + 1];
        }
        out[n] = swr / sw;
    }
}

extern "C" void kernel_launch(void* const* d_in, const int* in_sizes, int n_in,
                              void* d_out, int out_size, void* d_ws, size_t ws_size,
                              hipStream_t stream)
{
    const float* embeds       = (const float*)d_in[0];  // [2048,128]
    const float* base_embeds  = (const float*)d_in[1];  // [2048,128]
    const float* base_rewards = (const float*)d_in[2];  // [2048]
    const float* W1           = (const float*)d_in[3];  // [128,128] (in,out)
    const float* w2           = (const float*)d_in[4];  // [128,1]
    float* out = (float*)d_out;

    // ws: partials [2048*MT*2] | A1W | AEW | B1W | BE (each 2048*128) | w2sum[1]
    float* partials = (float*)d_ws;
    float* A1W = partials + (size_t)NROWS * MT * 2;
    float* AEW = A1W + (size_t)NROWS * F;
    float* B1W = AEW + (size_t)NROWS * F;
    float* BEp = B1W + (size_t)MROWS * F;
    float* w2s = BEp + (size_t)MROWS * F;

    proj_kernel<<<(NROWS + MROWS) / 2, 256, 0, stream>>>(
        embeds, base_embeds, W1, w2, A1W, AEW, B1W, BEp, w2s);

    dim3 grid2(NROWS / BN, MROWS / BM);
    pair_kernel<<<grid2, 64, 0, stream>>>(A1W, AEW, B1W, BEp, w2, w2s, base_rewards, partials);

    finalize_kernel<<<(NROWS + 255) / 256, 256, 0, stream>>>(partials, out);
}